// Round 2
// baseline (825.974 us; speedup 1.0000x reference)
//
#include <hip/hip_runtime.h>
#include <cstdint>

// BloomEmbedding: 4 hash functions, table [4][1e6][32] f32, out [N][128] f32.
//
// v2 strategy: the gather is DRAM-activation-bound when it randomly hits the
// full 512 MB table (no L3 retention). Split into 4 per-table passes:
//   pass h: (1) stream table h sequentially -> populates 256 MB Infinity Cache
//           (2) gather all N rows for hash h -> random reads hit L3
// Output stores are non-temporal so the 105 MB/pass write stream does not
// evict the table from L3. Launches on one stream serialize (graph-safe).

#define TABLE_SIZE 1000000u
#define SEED 42u

// Native clang vector type: __builtin_nontemporal_store requires it
// (HIP's float4 is a class and is rejected).
typedef float vfloat4 __attribute__((ext_vector_type(4)));

__device__ __forceinline__ uint32_t hash_id(uint32_t x) {
    x ^= x >> 16;
    x *= 0x7FEB352Du;
    x ^= x >> 15;
    x *= 0x846CA68Bu;
    x ^= x >> 16;
    return x % TABLE_SIZE;
}

// Stream one 128 MB table (TABLE_SIZE*8 float4) sequentially to warm the
// Infinity Cache. Loads kept live via empty asm (no DCE), nothing written.
__global__ void __launch_bounds__(256) warm_kernel(const vfloat4* __restrict__ tab,
                                                   int nvec) {
    float acc = 0.0f;
    const int stride = gridDim.x * blockDim.x;
    for (int i = blockIdx.x * blockDim.x + threadIdx.x; i < nvec; i += stride) {
        const vfloat4 v = tab[i];
        acc += v.x + v.y + v.z + v.w;
    }
    asm volatile("" :: "v"(acc));  // keep the loads observable
}

// One hash per launch. 8 threads per id; each thread moves one float4 (16 B).
// A wave64 covers 8 ids -> 8 distinct 128 B rows (full cache lines).
// Writes: out[gid][h*8 + d4] -> 128 B contiguous per id, full lines, nt.
__global__ void __launch_bounds__(256) gather_kernel(const int* __restrict__ ids,
                                                     const vfloat4* __restrict__ tab,
                                                     vfloat4* __restrict__ out,
                                                     int n, uint32_t seed_h, int h) {
    const int tid = blockIdx.x * blockDim.x + threadIdx.x;
    const int gid = tid >> 3;   // id index
    if (gid >= n) return;
    const int d4 = tid & 7;     // float4 index within 32-f32 sub-row

    const uint32_t idx = hash_id((uint32_t)ids[gid] + seed_h);
    const vfloat4 v = tab[(size_t)idx * 8 + (size_t)d4];
    __builtin_nontemporal_store(v, &out[(size_t)gid * 32 + (size_t)(h * 8 + d4)]);
}

extern "C" void kernel_launch(void* const* d_in, const int* in_sizes, int n_in,
                              void* d_out, int out_size, void* d_ws, size_t ws_size,
                              hipStream_t stream) {
    const int*     ids    = (const int*)d_in[0];
    const vfloat4* tables = (const vfloat4*)d_in[1];
    vfloat4*       out    = (vfloat4*)d_out;

    const int n = in_sizes[0];                       // 819200 ids
    const int nvec = (int)(TABLE_SIZE * 8u);         // 8M float4 per table

    const long long gthreads = (long long)n * 8;
    const int gblock = 256;
    const int ggrid  = (int)((gthreads + gblock - 1) / gblock);

    for (int h = 0; h < 4; ++h) {
        const vfloat4* tab = tables + (size_t)h * TABLE_SIZE * 8;
        warm_kernel<<<2048, 256, 0, stream>>>(tab, nvec);
        gather_kernel<<<ggrid, gblock, 0, stream>>>(ids, tab, out, n,
                                                    SEED + (uint32_t)h, h);
    }
}